// Round 7
// baseline (164.306 us; speedup 1.0000x reference)
//
#include <hip/hip_runtime.h>

#define KEHALF 7.199822675975274f
#define CUTOFF 12.0f
#define ITER 4

typedef float    fx4 __attribute__((ext_vector_type(4)));
typedef int      ix4 __attribute__((ext_vector_type(4)));
typedef int      ix2 __attribute__((ext_vector_type(2)));
typedef _Float16 hx4 __attribute__((ext_vector_type(4)));
typedef _Float16 hx8 __attribute__((ext_vector_type(8)));

static __device__ __forceinline__ hx4 as_h4(ix2 v) { union { ix2 i; hx4 h; } u; u.i = v; return u.h; }
static __device__ __forceinline__ hx8 as_h8(ix4 v) { union { ix4 i; hx8 h; } u; u.i = v; return u.h; }

// ---- Pack kernel: T[atom] = 16 halves (32B): [q, mu(3), Q(9), pad(3)] ----
__global__ __launch_bounds__(256)
void pack_atoms_half(const float* __restrict__ q,
                     const float* __restrict__ mu,
                     const float* __restrict__ quad,
                     _Float16* __restrict__ T, int N) {
    int a = blockIdx.x * blockDim.x + threadIdx.x;
    if (a >= N) return;
    const float* m = mu + 3 * a;
    const float* Q = quad + 9 * a;
    hx8 t0, t1;
    t0[0] = (_Float16)q[a];
    t0[1] = (_Float16)m[0]; t0[2] = (_Float16)m[1]; t0[3] = (_Float16)m[2];
    t0[4] = (_Float16)Q[0]; t0[5] = (_Float16)Q[1]; t0[6] = (_Float16)Q[2]; t0[7] = (_Float16)Q[3];
    t1[0] = (_Float16)Q[4]; t1[1] = (_Float16)Q[5]; t1[2] = (_Float16)Q[6]; t1[3] = (_Float16)Q[7];
    t1[4] = (_Float16)Q[8]; t1[5] = (_Float16)0.0f; t1[6] = (_Float16)0.0f; t1[7] = (_Float16)0.0f;
    hx8* dst = reinterpret_cast<hx8*>(T + 16 * a);
    dst[0] = t0; dst[1] = t1;
}

struct SRegs { ix4 u4, v4; fx4 d4, va, vb, vc; };
struct GRegs { ix2 gu[4]; ix4 gv0[4], gv1[4]; };

static __device__ __forceinline__ void issueS(SRegs& S,
                                              const float* __restrict__ dist,
                                              const float* __restrict__ vec,
                                              const int* __restrict__ iu,
                                              const int* __restrict__ iv, int e0) {
    S.u4 = __builtin_nontemporal_load(reinterpret_cast<const ix4*>(iu + e0));
    S.v4 = __builtin_nontemporal_load(reinterpret_cast<const ix4*>(iv + e0));
    S.d4 = __builtin_nontemporal_load(reinterpret_cast<const fx4*>(dist + e0));
    S.va = __builtin_nontemporal_load(reinterpret_cast<const fx4*>(vec + 3 * e0));
    S.vb = __builtin_nontemporal_load(reinterpret_cast<const fx4*>(vec + 3 * e0 + 4));
    S.vc = __builtin_nontemporal_load(reinterpret_cast<const fx4*>(vec + 3 * e0 + 8));
}

static __device__ __forceinline__ void issueG(GRegs& G, const _Float16* __restrict__ T,
                                              const SRegs& S) {
    int ub[4]  = {S.u4.x, S.u4.y, S.u4.z, S.u4.w};
    int vbi[4] = {S.v4.x, S.v4.y, S.v4.z, S.v4.w};
#pragma unroll
    for (int k = 0; k < 4; ++k) {
        const _Float16* pu = T + ((long)ub[k] << 4);
        const _Float16* pv = T + ((long)vbi[k] << 4);
        G.gu[k]  = *reinterpret_cast<const ix2*>(pu);
        G.gv0[k] = *reinterpret_cast<const ix4*>(pv);
        G.gv1[k] = *reinterpret_cast<const ix4*>(pv + 8);
    }
}

// Pin: wait only on CURRENT batch data (ready), forbid sinking newer loads below.
#define PIN(S, G) asm volatile("" : \
    "+v"((S).d4), "+v"((S).va), "+v"((S).vb), "+v"((S).vc), \
    "+v"((G).gu[0]), "+v"((G).gu[1]), "+v"((G).gu[2]), "+v"((G).gu[3]), \
    "+v"((G).gv0[0]), "+v"((G).gv0[1]), "+v"((G).gv0[2]), "+v"((G).gv0[3]), \
    "+v"((G).gv1[0]), "+v"((G).gv1[1]), "+v"((G).gv1[2]), "+v"((G).gv1[3]) :: "memory")

static __device__ __forceinline__ fx4 computeBatch(const SRegs& S, const GRegs& G) {
    float db[4]   = {S.d4.x, S.d4.y, S.d4.z, S.d4.w};
    float vvv[12] = {S.va.x, S.va.y, S.va.z, S.va.w,
                     S.vb.x, S.vb.y, S.vb.z, S.vb.w,
                     S.vc.x, S.vc.y, S.vc.z, S.vc.w};
    float res[4];
#pragma unroll
    for (int k = 0; k < 4; ++k) {
        float d = db[k];
        float vx = vvv[3 * k + 0], vy = vvv[3 * k + 1], vz = vvv[3 * k + 2];
        hx4 au  = as_h4(G.gu[k]);
        hx8 bv0 = as_h8(G.gv0[k]);
        hx8 bv1 = as_h8(G.gv1[k]);

        float inv_d = __builtin_amdgcn_rcpf(d);
        float x = fminf(fmaxf(d * 0.5f, 0.0f), 1.0f);
        float x2 = x * x;
        float x3 = x2 * x;
        float sw = 1.0f - x3 * (10.0f - 15.0f * x + 6.0f * x2);
        float chi = sw * __builtin_amdgcn_rsqf(d * d + 1.0f) + (1.0f - sw) * inv_d;
        float chi2 = chi * chi;
        float chi3 = chi2 * chi;

        float qu    = (float)au[0];
        float mux_u = (float)au[1], muy_u = (float)au[2], muz_u = (float)au[3];
        float qv    = (float)bv0[0];
        float mux_v = (float)bv0[1], muy_v = (float)bv0[2], muz_v = (float)bv0[3];
        float q00 = (float)bv0[4], q01 = (float)bv0[5], q02 = (float)bv0[6];
        float q10 = (float)bv0[7];
        float q11 = (float)bv1[0], q12 = (float)bv1[1], q20 = (float)bv1[2];
        float q21 = (float)bv1[3], q22 = (float)bv1[4];

        float dot_uv = (vx * mux_v + vy * muy_v + vz * muz_v) * inv_d;
        float dot_vu = (vx * mux_u + vy * muy_u + vz * muz_u) * inv_d;
        float mudot  = mux_u * mux_v + muy_u * muy_v + muz_u * muz_v;

        float Eelec = qu * qv * chi
                    + 2.0f * qu * dot_uv * chi2
                    + (mudot - 3.0f * dot_uv * dot_vu) * chi3;

        float s = vx * (vx * q00 + vy * q01 + vz * q02)
                + vy * (vx * q10 + vy * q11 + vz * q12)
                + vz * (vx * q20 + vy * q21 + vz * q22);
        float tr = q00 + q11 + q22;
        float n2 = vx * vx + vy * vy + vz * vz;
        float sum_uv = (s - n2 * (1.0f / 3.0f) * tr) * (inv_d * inv_d);

        Eelec += qu * sum_uv * chi3;
        res[k] = (d <= CUTOFF) ? (KEHALF * Eelec) : 0.0f;
    }
    fx4 o = {res[0], res[1], res[2], res[3]};
    return o;
}

// ---- Main kernel: software-pipelined batches (gathers 1 ahead, streaming 2 ahead) ----
__global__ __launch_bounds__(256, 3)
void damped_elec_pipe(const float* __restrict__ dist,
                      const float* __restrict__ vec,
                      const _Float16* __restrict__ T,
                      const int* __restrict__ iu,
                      const int* __restrict__ iv,
                      float* __restrict__ out, int E, int NTh) {
    int tid = blockIdx.x * blockDim.x + threadIdx.x;
    int NB = E >> 2;  // full 4-edge batches

    // Tail edges (E % 4) handled scalar by thread 0.
    if (tid == 0) {
        for (int e = NB << 2; e < E; ++e) {
            float d = dist[e];
            int u = iu[e], v = iv[e];
            float vx = vec[3 * e + 0], vy = vec[3 * e + 1], vz = vec[3 * e + 2];
            const _Float16* Tu = T + ((long)u << 4);
            const _Float16* Tv = T + ((long)v << 4);
            float inv_d = 1.0f / d;
            float x = fminf(fmaxf(d * 0.5f, 0.0f), 1.0f);
            float x2 = x * x, x3 = x2 * x;
            float sw = 1.0f - x3 * (10.0f - 15.0f * x + 6.0f * x2);
            float chi = sw / sqrtf(d * d + 1.0f) + (1.0f - sw) * inv_d;
            float chi2 = chi * chi, chi3 = chi2 * chi;
            float qu = (float)Tu[0], qv = (float)Tv[0];
            float dot_uv = (vx * (float)Tv[1] + vy * (float)Tv[2] + vz * (float)Tv[3]) * inv_d;
            float dot_vu = (vx * (float)Tu[1] + vy * (float)Tu[2] + vz * (float)Tu[3]) * inv_d;
            float mudot  = (float)Tu[1] * (float)Tv[1] + (float)Tu[2] * (float)Tv[2]
                         + (float)Tu[3] * (float)Tv[3];
            float Eelec = qu * qv * chi + 2.0f * qu * dot_uv * chi2
                        + (mudot - 3.0f * dot_uv * dot_vu) * chi3;
            float s = vx * (vx * (float)Tv[4] + vy * (float)Tv[5] + vz * (float)Tv[6])
                    + vy * (vx * (float)Tv[7] + vy * (float)Tv[8] + vz * (float)Tv[9])
                    + vz * (vx * (float)Tv[10] + vy * (float)Tv[11] + vz * (float)Tv[12]);
            float tr = (float)Tv[4] + (float)Tv[8] + (float)Tv[12];
            float n2 = vx * vx + vy * vy + vz * vz;
            float sum_uv = (s - n2 * (1.0f / 3.0f) * tr) * (inv_d * inv_d);
            Eelec += qu * sum_uv * chi3;
            out[e] = (d <= CUTOFF) ? (KEHALF * Eelec) : 0.0f;
        }
    }
    if (tid >= NB) return;

    int  b[ITER];
    bool wr[ITER];
#pragma unroll
    for (int i = 0; i < ITER; ++i) {
        long bi = (long)tid + (long)i * NTh;
        wr[i] = bi < NB;
        b[i]  = wr[i] ? (int)bi : (NB - 1);  // clamp: loads harmless, stores guarded
    }

    SRegs S[ITER];
    GRegs G[ITER];

    // Prologue: batch0 streaming + gathers; batch1 streaming.
    issueS(S[0], dist, vec, iu, iv, b[0] * 4);
    issueG(G[0], T, S[0]);
    if (ITER > 1) issueS(S[1], dist, vec, iu, iv, b[1] * 4);

#pragma unroll
    for (int i = 0; i < ITER; ++i) {
        if (i + 1 < ITER) issueG(G[i + 1], T, S[i + 1]);
        if (i + 2 < ITER) issueS(S[i + 2], dist, vec, iu, iv, b[i + 2] * 4);
        PIN(S[i], G[i]);
        fx4 o4 = computeBatch(S[i], G[i]);
        if (wr[i]) __builtin_nontemporal_store(o4, reinterpret_cast<fx4*>(out + b[i] * 4));
    }
}

// ---- Fallback (ws too small): direct scalar-gather kernel ----
__global__ __launch_bounds__(256)
void damped_elec_direct(const float* __restrict__ dist,
                        const float* __restrict__ vec,
                        const float* __restrict__ q,
                        const float* __restrict__ mu,
                        const float* __restrict__ quad,
                        const int* __restrict__ idx_u,
                        const int* __restrict__ idx_v,
                        float* __restrict__ out, int E) {
    int e = blockIdx.x * blockDim.x + threadIdx.x;
    if (e >= E) return;
    float d = dist[e];
    int u = idx_u[e], v = idx_v[e];
    float vx = vec[3 * e + 0], vy = vec[3 * e + 1], vz = vec[3 * e + 2];

    float inv_d = 1.0f / d;
    float x = fminf(fmaxf(d * 0.5f, 0.0f), 1.0f);
    float x2 = x * x, x3 = x2 * x;
    float sw = 1.0f - x3 * (10.0f - 15.0f * x + 6.0f * x2);
    float chi = sw / sqrtf(d * d + 1.0f) + (1.0f - sw) * inv_d;
    float chi2 = chi * chi, chi3 = chi2 * chi;

    float qu = q[u], qv = q[v];
    const float* mu_u = mu + 3 * u;
    const float* mu_v = mu + 3 * v;
    float dot_uv = (vx * mu_v[0] + vy * mu_v[1] + vz * mu_v[2]) * inv_d;
    float dot_vu = (vx * mu_u[0] + vy * mu_u[1] + vz * mu_u[2]) * inv_d;
    float mudot  = mu_u[0] * mu_v[0] + mu_u[1] * mu_v[1] + mu_u[2] * mu_v[2];

    float Eelec = qu * qv * chi
                + 2.0f * qu * dot_uv * chi2
                + (mudot - 3.0f * dot_uv * dot_vu) * chi3;

    const float* Qv = quad + 9 * v;
    float s = vx * (vx * Qv[0] + vy * Qv[1] + vz * Qv[2])
            + vy * (vx * Qv[3] + vy * Qv[4] + vz * Qv[5])
            + vz * (vx * Qv[6] + vy * Qv[7] + vz * Qv[8]);
    float tr = Qv[0] + Qv[4] + Qv[8];
    float n2 = vx * vx + vy * vy + vz * vz;
    float sum_uv = (s - n2 * (1.0f / 3.0f) * tr) * (inv_d * inv_d);

    Eelec += qu * sum_uv * chi3;
    out[e] = (d <= CUTOFF) ? (KEHALF * Eelec) : 0.0f;
}

extern "C" void kernel_launch(void* const* d_in, const int* in_sizes, int n_in,
                              void* d_out, int out_size, void* d_ws, size_t ws_size,
                              hipStream_t stream) {
    const float* dist  = (const float*)d_in[0];
    const float* vec   = (const float*)d_in[1];
    const float* q     = (const float*)d_in[2];
    const float* mu    = (const float*)d_in[3];
    const float* quad  = (const float*)d_in[4];
    const int*   idx_u = (const int*)d_in[5];
    const int*   idx_v = (const int*)d_in[6];
    float* out = (float*)d_out;

    int E = in_sizes[0];
    int N = in_sizes[2];  // atomic_charges count == N_ATOMS

    size_t need = (size_t)N * 16 * sizeof(_Float16);
    if (ws_size >= need) {
        _Float16* T = (_Float16*)d_ws;
        pack_atoms_half<<<(N + 255) / 256, 256, 0, stream>>>(q, mu, quad, T, N);
        int NB = E >> 2;
        int threads_needed = (NB + ITER - 1) / ITER;
        int blocks = (threads_needed + 255) / 256;
        if (blocks < 1) blocks = 1;
        int NTh = blocks * 256;
        damped_elec_pipe<<<blocks, 256, 0, stream>>>(dist, vec, T, idx_u, idx_v,
                                                     out, E, NTh);
    } else {
        damped_elec_direct<<<(E + 255) / 256, 256, 0, stream>>>(
            dist, vec, q, mu, quad, idx_u, idx_v, out, E);
    }
}

// Round 8
// 142.887 us; speedup vs baseline: 1.1499x; 1.1499x over previous
//
#include <hip/hip_runtime.h>

#define KEHALF 7.199822675975274f
#define CUTOFF 12.0f

typedef float    fx4 __attribute__((ext_vector_type(4)));
typedef int      ix4 __attribute__((ext_vector_type(4)));
typedef int      ix2 __attribute__((ext_vector_type(2)));
typedef _Float16 hx4 __attribute__((ext_vector_type(4)));

static __device__ __forceinline__ hx4 as_h4(ix2 v) { union { ix2 i; hx4 h; } u; u.i = v; return u.h; }
static __device__ __forceinline__ float h2f_bits(unsigned int hb) {
    union { unsigned short u; _Float16 h; } c; c.u = (unsigned short)hb; return (float)c.h;
}
static __device__ __forceinline__ unsigned int f2h_bits(float f) {
    union { _Float16 h; unsigned short u; } c; c.h = (_Float16)f; return (unsigned int)c.u;
}

// ---- Pack kernel: T[atom] = 16 B: d0,d1 = {q,mu} fp16; d2,d3 = 5 quad vals
// (traceless-symmetric reduced) at 13/12-bit rounded fp16.
// Table = 100K * 16 B = 1.6 MB -> fully L2-resident per XCD.
__global__ __launch_bounds__(256)
void pack_atoms16(const float* __restrict__ q,
                  const float* __restrict__ mu,
                  const float* __restrict__ quad,
                  unsigned int* __restrict__ T, int N) {
    int a = blockIdx.x * blockDim.x + threadIdx.x;
    if (a >= N) return;
    const float* m = mu + 3 * a;
    const float* Q = quad + 9 * a;
    float Q00 = Q[0], Q01 = Q[1], Q02 = Q[2];
    float Q10 = Q[3], Q11 = Q[4], Q12 = Q[5];
    float Q20 = Q[6], Q21 = Q[7], Q22 = Q[8];
    float tr3 = (Q00 + Q11 + Q22) * (1.0f / 3.0f);
    // 13-bit: (fp16bits + 4) >> 3 (round-to-nearest on 3 dropped mantissa bits)
    unsigned int t00 = ((f2h_bits(Q00 - tr3) + 4u) >> 3) & 0x1FFFu;
    unsigned int t11 = ((f2h_bits(Q11 - tr3) + 4u) >> 3) & 0x1FFFu;
    unsigned int t01 = ((f2h_bits(Q01 + Q10) + 4u) >> 3) & 0x1FFFu;
    unsigned int t02 = ((f2h_bits(Q02 + Q20) + 4u) >> 3) & 0x1FFFu;
    unsigned int t12 = ((f2h_bits(Q12 + Q21) + 8u) >> 4) & 0xFFFu;  // 12-bit
    unsigned int d0 = f2h_bits(q[a]) | (f2h_bits(m[0]) << 16);
    unsigned int d1 = f2h_bits(m[1]) | (f2h_bits(m[2]) << 16);
    unsigned int d2 = t00 | (t11 << 13) | ((t12 & 0x3Fu) << 26);
    unsigned int d3 = t01 | (t02 << 13) | ((t12 >> 6) << 26);
    ix4 e = {(int)d0, (int)d1, (int)d2, (int)d3};
    *reinterpret_cast<ix4*>(T + 4 * (long)a) = e;
}

// ---- Per-edge physics (decodes packed v-entry) ----
static __device__ __forceinline__ float edgeE(float d, float vx, float vy, float vz,
                                              hx4 au, ix4 gv) {
    float inv_d = __builtin_amdgcn_rcpf(d);
    float x = fminf(fmaxf(d * 0.5f, 0.0f), 1.0f);
    float x2 = x * x, x3 = x2 * x;
    float sw = 1.0f - x3 * (10.0f - 15.0f * x + 6.0f * x2);
    float chi = sw * __builtin_amdgcn_rsqf(d * d + 1.0f) + (1.0f - sw) * inv_d;
    float chi2 = chi * chi, chi3 = chi2 * chi;

    float qu    = (float)au[0];
    float mux_u = (float)au[1], muy_u = (float)au[2], muz_u = (float)au[3];

    ix2 vlo = {gv.x, gv.y};
    hx4 av = as_h4(vlo);
    float qv    = (float)av[0];
    float mux_v = (float)av[1], muy_v = (float)av[2], muz_v = (float)av[3];

    unsigned int d2b = (unsigned int)gv.z, d3b = (unsigned int)gv.w;
    float p00 = h2f_bits((d2b & 0x1FFFu) << 3);
    float p11 = h2f_bits(((d2b >> 13) & 0x1FFFu) << 3);
    float s01 = h2f_bits((d3b & 0x1FFFu) << 3);
    float s02 = h2f_bits(((d3b >> 13) & 0x1FFFu) << 3);
    float s12 = h2f_bits((((d3b >> 26) << 6) | (d2b >> 26)) << 4);
    float p22 = -(p00 + p11);  // traceless: exact reconstruction

    float dot_uv = (vx * mux_v + vy * muy_v + vz * muz_v) * inv_d;
    float dot_vu = (vx * mux_u + vy * muy_u + vz * muz_u) * inv_d;
    float mudot  = mux_u * mux_v + muy_u * muy_v + muz_u * muz_v;

    float E = qu * qv * chi
            + 2.0f * qu * dot_uv * chi2
            + (mudot - 3.0f * dot_uv * dot_vu) * chi3;

    float s = vx * (vx * p00 + vy * s01 + vz * s02)
            + vy * (vy * p11 + vz * s12)
            + vz * (vz * p22);
    E += qu * (s * inv_d * inv_d) * chi3;
    return (d <= CUTOFF) ? (KEHALF * E) : 0.0f;
}

// ---- Main kernel: round-6 single-window structure, 2 gather requests/edge ----
__global__ __launch_bounds__(256)
void damped_elec_p16(const float* __restrict__ dist,
                     const float* __restrict__ vec,
                     const unsigned int* __restrict__ T,
                     const int* __restrict__ iu,
                     const int* __restrict__ iv,
                     float* __restrict__ out, int E) {
    int t = blockIdx.x * blockDim.x + threadIdx.x;
    int e0 = t * 4;
    if (e0 >= E) return;

    if (e0 + 4 <= E) {
        // Index loads first (head of critical chain) — normal caching.
        ix4 u4 = *reinterpret_cast<const ix4*>(iu + e0);
        ix4 v4 = *reinterpret_cast<const ix4*>(iv + e0);
        // Pure streaming data: non-temporal (keep L2 for the atom table).
        fx4 d4 = __builtin_nontemporal_load(reinterpret_cast<const fx4*>(dist + e0));
        fx4 va = __builtin_nontemporal_load(reinterpret_cast<const fx4*>(vec + 3 * e0));
        fx4 vb = __builtin_nontemporal_load(reinterpret_cast<const fx4*>(vec + 3 * e0 + 4));
        fx4 vc = __builtin_nontemporal_load(reinterpret_cast<const fx4*>(vec + 3 * e0 + 8));

        int ub[4]  = {u4.x, u4.y, u4.z, u4.w};
        int vbi[4] = {v4.x, v4.y, v4.z, v4.w};

        // Gather phase: 2 loads per edge (u: 8 B, v: 16 B), all issued back-to-back.
        ix2 gu[4];
        ix4 gv[4];
#pragma unroll
        for (int k = 0; k < 4; ++k) {
            const unsigned int* pu = T + ((long)ub[k] << 2);
            const unsigned int* pv = T + ((long)vbi[k] << 2);
            gu[k] = *reinterpret_cast<const ix2*>(pu);
            gv[k] = *reinterpret_cast<const ix4*>(pv);
        }

        // Keep-live fence: one latency window, no sinking into compute.
        asm volatile("" : "+v"(d4), "+v"(va), "+v"(vb), "+v"(vc),
                          "+v"(gu[0]), "+v"(gu[1]), "+v"(gu[2]), "+v"(gu[3]),
                          "+v"(gv[0]), "+v"(gv[1]), "+v"(gv[2]), "+v"(gv[3]) :: "memory");

        float db[4]   = {d4.x, d4.y, d4.z, d4.w};
        float vvv[12] = {va.x, va.y, va.z, va.w,
                         vb.x, vb.y, vb.z, vb.w,
                         vc.x, vc.y, vc.z, vc.w};

        float res[4];
#pragma unroll
        for (int k = 0; k < 4; ++k) {
            res[k] = edgeE(db[k], vvv[3 * k + 0], vvv[3 * k + 1], vvv[3 * k + 2],
                           as_h4(gu[k]), gv[k]);
        }
        fx4 o4 = {res[0], res[1], res[2], res[3]};
        __builtin_nontemporal_store(o4, reinterpret_cast<fx4*>(out + e0));
    } else {
        // Scalar tail (E % 4 != 0 only).
        for (int e = e0; e < E; ++e) {
            int u = iu[e], v = iv[e];
            ix2 gu = *reinterpret_cast<const ix2*>(T + ((long)u << 2));
            ix4 gv = *reinterpret_cast<const ix4*>(T + ((long)v << 2));
            out[e] = edgeE(dist[e], vec[3 * e + 0], vec[3 * e + 1], vec[3 * e + 2],
                           as_h4(gu), gv);
        }
    }
}

// ---- Fallback (ws too small): direct scalar-gather kernel ----
__global__ __launch_bounds__(256)
void damped_elec_direct(const float* __restrict__ dist,
                        const float* __restrict__ vec,
                        const float* __restrict__ q,
                        const float* __restrict__ mu,
                        const float* __restrict__ quad,
                        const int* __restrict__ idx_u,
                        const int* __restrict__ idx_v,
                        float* __restrict__ out, int E) {
    int e = blockIdx.x * blockDim.x + threadIdx.x;
    if (e >= E) return;
    float d = dist[e];
    int u = idx_u[e], v = idx_v[e];
    float vx = vec[3 * e + 0], vy = vec[3 * e + 1], vz = vec[3 * e + 2];

    float inv_d = 1.0f / d;
    float x = fminf(fmaxf(d * 0.5f, 0.0f), 1.0f);
    float x2 = x * x, x3 = x2 * x;
    float sw = 1.0f - x3 * (10.0f - 15.0f * x + 6.0f * x2);
    float chi = sw / sqrtf(d * d + 1.0f) + (1.0f - sw) * inv_d;
    float chi2 = chi * chi, chi3 = chi2 * chi;

    float qu = q[u], qv = q[v];
    const float* mu_u = mu + 3 * u;
    const float* mu_v = mu + 3 * v;
    float dot_uv = (vx * mu_v[0] + vy * mu_v[1] + vz * mu_v[2]) * inv_d;
    float dot_vu = (vx * mu_u[0] + vy * mu_u[1] + vz * mu_u[2]) * inv_d;
    float mudot  = mu_u[0] * mu_v[0] + mu_u[1] * mu_v[1] + mu_u[2] * mu_v[2];

    float Eelec = qu * qv * chi
                + 2.0f * qu * dot_uv * chi2
                + (mudot - 3.0f * dot_uv * dot_vu) * chi3;

    const float* Qv = quad + 9 * v;
    float s = vx * (vx * Qv[0] + vy * Qv[1] + vz * Qv[2])
            + vy * (vx * Qv[3] + vy * Qv[4] + vz * Qv[5])
            + vz * (vx * Qv[6] + vy * Qv[7] + vz * Qv[8]);
    float tr = Qv[0] + Qv[4] + Qv[8];
    float n2 = vx * vx + vy * vy + vz * vz;
    float sum_uv = (s - n2 * (1.0f / 3.0f) * tr) * (inv_d * inv_d);

    Eelec += qu * sum_uv * chi3;
    out[e] = (d <= CUTOFF) ? (KEHALF * Eelec) : 0.0f;
}

extern "C" void kernel_launch(void* const* d_in, const int* in_sizes, int n_in,
                              void* d_out, int out_size, void* d_ws, size_t ws_size,
                              hipStream_t stream) {
    const float* dist  = (const float*)d_in[0];
    const float* vec   = (const float*)d_in[1];
    const float* q     = (const float*)d_in[2];
    const float* mu    = (const float*)d_in[3];
    const float* quad  = (const float*)d_in[4];
    const int*   idx_u = (const int*)d_in[5];
    const int*   idx_v = (const int*)d_in[6];
    float* out = (float*)d_out;

    int E = in_sizes[0];
    int N = in_sizes[2];  // atomic_charges count == N_ATOMS

    size_t need = (size_t)N * 16;  // 16 B per atom
    if (ws_size >= need) {
        unsigned int* T = (unsigned int*)d_ws;
        pack_atoms16<<<(N + 255) / 256, 256, 0, stream>>>(q, mu, quad, T, N);
        int threads = (E + 3) / 4;
        damped_elec_p16<<<(threads + 255) / 256, 256, 0, stream>>>(
            dist, vec, T, idx_u, idx_v, out, E);
    } else {
        damped_elec_direct<<<(E + 255) / 256, 256, 0, stream>>>(
            dist, vec, q, mu, quad, idx_u, idx_v, out, E);
    }
}